// Round 3
// baseline (596.278 us; speedup 1.0000x reference)
//
#include <hip/hip_runtime.h>
#include <stdint.h>

// Problem constants
#define B_SZ 4
#define S_LEN 2048
#define NH 16
#define HD 64
#define DM 1024

typedef __bf16 bf16;
typedef __bf16 bf16x8 __attribute__((ext_vector_type(8)));
typedef float f32x4 __attribute__((ext_vector_type(4)));

#define MFMA16(a, b, c) __builtin_amdgcn_mfma_f32_16x16x32_bf16(a, b, c, 0, 0, 0)

// load 8 consecutive f32 and round to bf16x8
__device__ __forceinline__ bf16x8 ldcvt(const float* p) {
  f32x4 u0 = *(const f32x4*)p;
  f32x4 u1 = *(const f32x4*)(p + 4);
  bf16x8 v;
#pragma unroll
  for (int j = 0; j < 4; j++) {
    v[j] = (bf16)u0[j];
    v[4 + j] = (bf16)u1[j];
  }
  return v;
}

// ---------------------------------------------------------------------------
// 128x128 GEMM core, BK=32, 4 waves each 64x64 (4x4 tiles of 16x16x32 bf16).
// C[m,n] = sum_k A[m,k] * B[n,k]  (both K-contiguous, lda=ldb=1024).
// AF32/BF32: whether the global source is f32 (converted during staging).
// ---------------------------------------------------------------------------
template <bool AF32, bool BF32>
__device__ __forceinline__ void gemm_core(const void* Agv, const void* Bgv,
                                          f32x4 acc[4][4], bf16* As, bf16* Bs) {
  const float* Af = (const float*)Agv;
  const bf16* Ab = (const bf16*)Agv;
  const float* Bf = (const float*)Bgv;
  const bf16* Bb = (const bf16*)Bgv;
  const int tid = threadIdx.x;
  const int lane = tid & 63;
  const int wave = tid >> 6;
  const int wm = (wave >> 1) * 64;
  const int wn = (wave & 1) * 64;
  const int col = lane & 15;
  const int kq = (lane >> 4) * 8;
  const int r0 = tid >> 2;       // staging row (pass 0)
  const int c0 = (tid & 3) * 8;  // staging col
#pragma unroll
  for (int i = 0; i < 4; i++)
#pragma unroll
    for (int j = 0; j < 4; j++) acc[i][j] = (f32x4){0.f, 0.f, 0.f, 0.f};

  for (int k0 = 0; k0 < 1024; k0 += 32) {
    bf16x8 a0, a1, b0, b1;
    if (AF32) {
      a0 = ldcvt(Af + (size_t)r0 * 1024 + k0 + c0);
      a1 = ldcvt(Af + (size_t)(r0 + 64) * 1024 + k0 + c0);
    } else {
      a0 = *(const bf16x8*)(Ab + (size_t)r0 * 1024 + k0 + c0);
      a1 = *(const bf16x8*)(Ab + (size_t)(r0 + 64) * 1024 + k0 + c0);
    }
    if (BF32) {
      b0 = ldcvt(Bf + (size_t)r0 * 1024 + k0 + c0);
      b1 = ldcvt(Bf + (size_t)(r0 + 64) * 1024 + k0 + c0);
    } else {
      b0 = *(const bf16x8*)(Bb + (size_t)r0 * 1024 + k0 + c0);
      b1 = *(const bf16x8*)(Bb + (size_t)(r0 + 64) * 1024 + k0 + c0);
    }
    __syncthreads();  // previous iteration's LDS reads complete
    *(bf16x8*)(As + tid * 8) = a0;         // As[r0][c0..c0+7]
    *(bf16x8*)(As + 2048 + tid * 8) = a1;  // As[r0+64][...]
    *(bf16x8*)(Bs + tid * 8) = b0;
    *(bf16x8*)(Bs + 2048 + tid * 8) = b1;
    __syncthreads();

    bf16x8 af[4], bfr[4];
#pragma unroll
    for (int i = 0; i < 4; i++)
      af[i] = *(const bf16x8*)(As + (wm + i * 16 + col) * 32 + kq);
#pragma unroll
    for (int j = 0; j < 4; j++)
      bfr[j] = *(const bf16x8*)(Bs + (wn + j * 16 + col) * 32 + kq);
#pragma unroll
    for (int i = 0; i < 4; i++)
#pragma unroll
      for (int j = 0; j < 4; j++)
        acc[i][j] = MFMA16(af[i], bfr[j], acc[i][j]);
  }
}

// ---------------------------------------------------------------------------
// Kernel 1: fused QKV projection (f32 in, bf16 out). grid (bcnt*16, 24).
// Writes Q,K,V (tensor t at ws + t*ten_stride) in pass-local [bcnt,H,S,D].
// ---------------------------------------------------------------------------
__global__ __launch_bounds__(256, 2) void qkv_gemm(
    const float* __restrict__ x, const float* __restrict__ wq,
    const float* __restrict__ wk, const float* __restrict__ wv,
    bf16* __restrict__ ws, size_t ten_stride) {
  __shared__ __align__(16) bf16 As[128 * 32];
  __shared__ __align__(16) bf16 Bs[128 * 32];
  const int bx = blockIdx.x;
  const int by = blockIdx.y;
  const int wsel = by >> 3;
  const int n0 = (by & 7) * 128;
  const float* W = (wsel == 0) ? wq : ((wsel == 1) ? wk : wv);
  bf16* dst = ws + (size_t)wsel * ten_stride;

  f32x4 acc[4][4];
  gemm_core<true, true>(x + (size_t)bx * 128 * 1024, W + (size_t)n0 * 1024,
                        acc, As, Bs);

  const int lane = threadIdx.x & 63;
  const int wave = threadIdx.x >> 6;
  const int wm = (wave >> 1) * 64, wn = (wave & 1) * 64;
  const int col = lane & 15, quad = lane >> 4;
#pragma unroll
  for (int i = 0; i < 4; i++) {
    const int m0 = bx * 128 + wm + i * 16 + quad * 4;
#pragma unroll
    for (int j = 0; j < 4; j++) {
      const int n = n0 + wn + j * 16 + col;  // within [0,1024)
      const int h = n >> 6, d = n & 63;
#pragma unroll
      for (int r = 0; r < 4; r++) {
        const int mm = m0 + r;  // pass-local row
        const int bl = mm >> 11, s = mm & 2047;
        dst[((((size_t)bl * NH + h) * S_LEN + s) << 6) + d] = (bf16)acc[i][j][r];
      }
    }
  }
}

// ---------------------------------------------------------------------------
// Kernel 2: RoPE in-place on Q,K (pass-local [bcnt,H,S,D], bf16).
// ---------------------------------------------------------------------------
__global__ void rope_kernel(bf16* __restrict__ q, bf16* __restrict__ k,
                            const int* __restrict__ tp) {
  const int idx = blockIdx.x * 256 + threadIdx.x;
  const int srow = idx >> 3;  // pass-local [0, bcnt*H*S)
  const int d0 = (idx & 7) * 8;
  const int s = srow & (S_LEN - 1);
  const float pf = (float)tp[s];
  const int i0 = d0 >> 1;
  float cs[4], sn[4];
#pragma unroll
  for (int j = 0; j < 4; j++) {
    // theta_i = 10000^{-i/32} = exp2(-i * log2(10000)/32)
    float freq = __builtin_exp2f(-(float)(i0 + j) * 0.41524101186091903f);
    float ang = pf * freq;
    sincosf(ang, &sn[j], &cs[j]);
  }
  const size_t off = (size_t)srow * 64 + d0;
  bf16x8 vq = *(bf16x8*)(q + off);
  bf16x8 vk = *(bf16x8*)(k + off);
#pragma unroll
  for (int j = 0; j < 4; j++) {
    float e = (float)vq[2 * j], o = (float)vq[2 * j + 1];
    vq[2 * j] = (bf16)(e * cs[j] - o * sn[j]);
    vq[2 * j + 1] = (bf16)(e * sn[j] + o * cs[j]);
    e = (float)vk[2 * j];
    o = (float)vk[2 * j + 1];
    vk[2 * j] = (bf16)(e * cs[j] - o * sn[j]);
    vk[2 * j + 1] = (bf16)(e * sn[j] + o * cs[j]);
  }
  *(bf16x8*)(q + off) = vq;
  *(bf16x8*)(k + off) = vk;
}

// ---------------------------------------------------------------------------
// Kernel 3: V [bh][S][D] -> Vt [bh][D][S] (bf16). grid (32, bcnt*16).
// ---------------------------------------------------------------------------
__global__ void transpose_v(const bf16* __restrict__ v, bf16* __restrict__ vt) {
  __shared__ __align__(16) bf16 t[64 * 72];  // [d][s_local], pitch 72
  const int st = blockIdx.x, bh = blockIdx.y;
  const bf16* src = v + ((size_t)bh * S_LEN + st * 64) * 64;
#pragma unroll
  for (int p = 0; p < 2; p++) {
    int g = p * 256 + threadIdx.x;
    int r = g >> 3, c = (g & 7) * 8;
    bf16x8 val = *(const bf16x8*)(src + r * 64 + c);
#pragma unroll
    for (int j = 0; j < 8; j++) t[(c + j) * 72 + r] = val[j];
  }
  __syncthreads();
  bf16* dst = vt + (size_t)bh * 64 * S_LEN + st * 64;
#pragma unroll
  for (int p = 0; p < 2; p++) {
    int g = p * 256 + threadIdx.x;
    int d = g >> 3, sc = (g & 7) * 8;
    *(bf16x8*)(dst + (size_t)d * S_LEN + sc) = *(const bf16x8*)(t + d * 72 + sc);
  }
}

// ---------------------------------------------------------------------------
// Kernel 4: causal flash attention (all bf16). grid (16 q-tiles rev, bcnt*16).
// 128 q-rows/block; 4 waves x 32 rows. Online softmax, exp2-based, scale
// folded (c = 0.125*log2e). O written pass-local [bcnt,S,H*D] bf16.
// LDS 64KB: Ks 16K | Vts 16K | Ps 32K (Qs aliases Ps; Q frags are in regs
// before the first in-loop barrier, P writes come two barriers later).
// ---------------------------------------------------------------------------
__global__ __launch_bounds__(256) void attn_kernel(
    const bf16* __restrict__ Q, const bf16* __restrict__ K,
    const bf16* __restrict__ Vt, bf16* __restrict__ O) {
  __shared__ __align__(16) bf16 smem[32768];  // 64 KB
  bf16* Ks = smem;           // [128][64]
  bf16* Vts = smem + 8192;   // [64][128]
  bf16* Ps = smem + 16384;   // [4][32][128]
  bf16* Qs = smem + 16384;   // alias of Ps

  const int tid = threadIdx.x, lane = tid & 63, wave = tid >> 6;
  const int col = lane & 15, quad = lane >> 4, kq = quad * 8;
  const int bh = blockIdx.y;                            // pass-local
  const int qt = (int)gridDim.x - 1 - (int)blockIdx.x;  // heavy blocks first
  const bf16* Qg = Q + ((size_t)bh * S_LEN + qt * 128) * 64;
  const bf16* Kg = K + (size_t)bh * S_LEN * 64;
  const bf16* Vg = Vt + (size_t)bh * 64 * S_LEN;

#pragma unroll
  for (int p = 0; p < 4; p++) {
    int g = p * 256 + tid;
    *(bf16x8*)(Qs + g * 8) = *(const bf16x8*)(Qg + (g >> 3) * 64 + (g & 7) * 8);
  }
  __syncthreads();
  const int wq0 = wave * 32;
  bf16x8 qf[2][2];
#pragma unroll
  for (int mi = 0; mi < 2; mi++)
#pragma unroll
    for (int kc = 0; kc < 2; kc++)
      qf[mi][kc] = *(const bf16x8*)(Qs + (wq0 + mi * 16 + col) * 64 + kc * 32 + kq);

  f32x4 oacc[2][4];
  float mst[2][4], lst[2][4];
#pragma unroll
  for (int mi = 0; mi < 2; mi++) {
#pragma unroll
    for (int nd = 0; nd < 4; nd++) oacc[mi][nd] = (f32x4){0.f, 0.f, 0.f, 0.f};
#pragma unroll
    for (int r = 0; r < 4; r++) { mst[mi][r] = -1e30f; lst[mi][r] = 0.f; }
  }
  const float CS = 0.18033688011112042f;  // 0.125 * log2(e)
  bf16* Pw = Ps + wave * 4096;

  for (int kt = 0; kt <= qt; kt++) {
    // register-mediated staging of K (128x64) and Vt (64x128)
    bf16x8 kreg[4], vreg[4];
#pragma unroll
    for (int p = 0; p < 4; p++) {
      int g = p * 256 + tid;
      kreg[p] = *(const bf16x8*)(Kg + (size_t)(kt * 128 + (g >> 3)) * 64 + (g & 7) * 8);
      vreg[p] = *(const bf16x8*)(Vg + (size_t)(g >> 4) * S_LEN + kt * 128 + (g & 15) * 8);
    }
    __syncthreads();  // previous iteration's LDS reads complete
#pragma unroll
    for (int p = 0; p < 4; p++) {
      int g = p * 256 + tid;
      *(bf16x8*)(Ks + g * 8) = kreg[p];
      *(bf16x8*)(Vts + g * 8) = vreg[p];
    }
    __syncthreads();

    // Scores: 2 m-tiles x 8 n-tiles, K=64 via 2 chained MFMAs
    f32x4 sa[2][8];
#pragma unroll
    for (int ni = 0; ni < 8; ni++) {
      bf16x8 kf0 = *(const bf16x8*)(Ks + (ni * 16 + col) * 64 + kq);
      bf16x8 kf1 = *(const bf16x8*)(Ks + (ni * 16 + col) * 64 + 32 + kq);
#pragma unroll
      for (int mi = 0; mi < 2; mi++) {
        f32x4 s = {0.f, 0.f, 0.f, 0.f};
        s = MFMA16(qf[mi][0], kf0, s);
        s = MFMA16(qf[mi][1], kf1, s);
        sa[mi][ni] = s;
      }
    }
    if (kt == qt) {  // causal mask on the diagonal tile
#pragma unroll
      for (int mi = 0; mi < 2; mi++) {
        const int qrow = wq0 + mi * 16 + quad * 4;
#pragma unroll
        for (int ni = 0; ni < 8; ni++) {
          const int kcol = ni * 16 + col;
#pragma unroll
          for (int r = 0; r < 4; r++)
            if (kcol > qrow + r) sa[mi][ni][r] = -1e30f;
        }
      }
    }
    // Online softmax per row (row = mi*16 + quad*4 + r; 16 lanes hold cols)
#pragma unroll
    for (int mi = 0; mi < 2; mi++) {
#pragma unroll
      for (int r = 0; r < 4; r++) {
        float mx = sa[mi][0][r];
#pragma unroll
        for (int ni = 1; ni < 8; ni++) mx = fmaxf(mx, sa[mi][ni][r]);
        mx = fmaxf(mx, __shfl_xor(mx, 1));
        mx = fmaxf(mx, __shfl_xor(mx, 2));
        mx = fmaxf(mx, __shfl_xor(mx, 4));
        mx = fmaxf(mx, __shfl_xor(mx, 8));
        float mnew = fmaxf(mst[mi][r], mx);
        float alpha = __builtin_exp2f((mst[mi][r] - mnew) * CS);
        mst[mi][r] = mnew;
        float rs = 0.f;
#pragma unroll
        for (int ni = 0; ni < 8; ni++) {
          float pv = __builtin_exp2f((sa[mi][ni][r] - mnew) * CS);
          sa[mi][ni][r] = pv;
          rs += pv;
        }
        rs += __shfl_xor(rs, 1);
        rs += __shfl_xor(rs, 2);
        rs += __shfl_xor(rs, 4);
        rs += __shfl_xor(rs, 8);
        lst[mi][r] = lst[mi][r] * alpha + rs;
#pragma unroll
        for (int nd = 0; nd < 4; nd++) oacc[mi][nd][r] *= alpha;
      }
    }
    // P: C-layout regs -> per-wave LDS [32][128] (A-layout readable)
#pragma unroll
    for (int mi = 0; mi < 2; mi++)
#pragma unroll
      for (int ni = 0; ni < 8; ni++)
#pragma unroll
        for (int r = 0; r < 4; r++)
          Pw[(mi * 16 + quad * 4 + r) * 128 + ni * 16 + col] = (bf16)sa[mi][ni][r];
    __syncthreads();  // order P writes before P reads (belt & suspenders)
    // O += P @ V  (contraction over 128 keys = 4 MFMA k-chunks)
#pragma unroll
    for (int kc = 0; kc < 4; kc++) {
      bf16x8 pf0 = *(const bf16x8*)(Pw + col * 128 + kc * 32 + kq);
      bf16x8 pf1 = *(const bf16x8*)(Pw + (16 + col) * 128 + kc * 32 + kq);
#pragma unroll
      for (int nd = 0; nd < 4; nd++) {
        bf16x8 vf = *(const bf16x8*)(Vts + (nd * 16 + col) * 128 + kc * 32 + kq);
        oacc[0][nd] = MFMA16(pf0, vf, oacc[0][nd]);
        oacc[1][nd] = MFMA16(pf1, vf, oacc[1][nd]);
      }
    }
  }

  // Epilogue: O[bl][s][h*64+d] = oacc / l  (bf16)
  const int bl = bh >> 4, h = bh & 15;
#pragma unroll
  for (int mi = 0; mi < 2; mi++) {
    float inv[4];
#pragma unroll
    for (int r = 0; r < 4; r++) inv[r] = 1.0f / lst[mi][r];
    const int srow0 = qt * 128 + wq0 + mi * 16 + quad * 4;
#pragma unroll
    for (int nd = 0; nd < 4; nd++)
#pragma unroll
      for (int r = 0; r < 4; r++)
        O[(size_t)(bl * S_LEN + srow0 + r) * DM + h * 64 + nd * 16 + col] =
            (bf16)(oacc[mi][nd][r] * inv[r]);
  }
}

// ---------------------------------------------------------------------------
// Kernel 5: output projection (A bf16, W f32, out f32). grid (bcnt*16, 8).
// ---------------------------------------------------------------------------
__global__ __launch_bounds__(256, 2) void out_gemm(const bf16* __restrict__ A,
                                                   const float* __restrict__ W,
                                                   float* __restrict__ out) {
  __shared__ __align__(16) bf16 As[128 * 32];
  __shared__ __align__(16) bf16 Bs[128 * 32];
  f32x4 acc[4][4];
  gemm_core<false, true>(A + (size_t)blockIdx.x * 128 * 1024,
                         W + (size_t)blockIdx.y * 128 * 1024, acc, As, Bs);
  const int lane = threadIdx.x & 63;
  const int wave = threadIdx.x >> 6;
  const int wm = (wave >> 1) * 64, wn = (wave & 1) * 64;
  const int col = lane & 15, quad = lane >> 4;
#pragma unroll
  for (int i = 0; i < 4; i++) {
    const int m0 = blockIdx.x * 128 + wm + i * 16 + quad * 4;
#pragma unroll
    for (int j = 0; j < 4; j++) {
      const int n = blockIdx.y * 128 + wn + j * 16 + col;
#pragma unroll
      for (int r = 0; r < 4; r++)
        out[(size_t)(m0 + r) * DM + n] = acc[i][j][r];
    }
  }
}

// ---------------------------------------------------------------------------
extern "C" void kernel_launch(void* const* d_in, const int* in_sizes, int n_in,
                              void* d_out, int out_size, void* d_ws,
                              size_t ws_size, hipStream_t stream) {
  const float* x = (const float*)d_in[0];
  const int* tp = (const int*)d_in[1];
  const float* wq = (const float*)d_in[2];
  const float* wk = (const float*)d_in[3];
  const float* wv = (const float*)d_in[4];
  const float* wo = (const float*)d_in[5];
  float* out = (float*)d_out;
  bf16* wsb = (bf16*)d_ws;

  const size_t TENb = (size_t)NH * S_LEN * HD;  // per-batch tensor: 4 MB bf16
  // workspace-adaptive batching: need 4 regions of bcnt*TENb bf16 each
  int bcnt = 1;
  if (ws_size >= 4 * 4 * TENb * sizeof(bf16)) bcnt = 4;       // 64 MB
  else if (ws_size >= 2 * 4 * TENb * sizeof(bf16)) bcnt = 2;  // 32 MB

  const size_t REG = (size_t)bcnt * TENb;
  bf16* Qw = wsb;             // [bcnt,H,S,D]
  bf16* Kw = wsb + REG;       // [bcnt,H,S,D]
  bf16* Vw = wsb + 2 * REG;   // [bcnt,H,S,D]
  bf16* Vtw = wsb + 3 * REG;  // [bcnt,H,D,S]
  bf16* Ow = Vw;              // [bcnt,S,H*D], aliases Vw (dead after transpose)

  for (int b0 = 0; b0 < B_SZ; b0 += bcnt) {
    const float* xb = x + (size_t)b0 * S_LEN * DM;
    float* outb = out + (size_t)b0 * S_LEN * DM;
    hipLaunchKernelGGL(qkv_gemm, dim3(bcnt * 16, 24), dim3(256), 0, stream,
                       xb, wq, wk, wv, Qw, REG);
    hipLaunchKernelGGL(rope_kernel, dim3(bcnt * 1024), dim3(256), 0, stream,
                       Qw, Kw, tp);
    hipLaunchKernelGGL(transpose_v, dim3(32, bcnt * 16), dim3(256), 0, stream,
                       Vw, Vtw);
    hipLaunchKernelGGL(attn_kernel, dim3(16, bcnt * 16), dim3(256), 0, stream,
                       Qw, Kw, Vtw, Ow);
    hipLaunchKernelGGL(out_gemm, dim3(bcnt * 16, 8), dim3(256), 0, stream,
                       Ow, wo, outb);
  }
}

// Round 4
// 307.982 us; speedup vs baseline: 1.9361x; 1.9361x over previous
//
#include <hip/hip_runtime.h>
#include <stdint.h>

// Problem constants
#define B_SZ 4
#define S_LEN 2048
#define NH 16
#define HD 64
#define DM 1024

typedef __bf16 bf16;
typedef __bf16 bf16x4 __attribute__((ext_vector_type(4)));
typedef __bf16 bf16x8 __attribute__((ext_vector_type(8)));
typedef float f32x4 __attribute__((ext_vector_type(4)));

#define MFMA16(a, b, c) __builtin_amdgcn_mfma_f32_16x16x32_bf16(a, b, c, 0, 0, 0)

// load 8 consecutive f32 and round to bf16x8
__device__ __forceinline__ bf16x8 ldcvt(const float* p) {
  f32x4 u0 = *(const f32x4*)p;
  f32x4 u1 = *(const f32x4*)(p + 4);
  bf16x8 v;
#pragma unroll
  for (int j = 0; j < 4; j++) {
    v[j] = (bf16)u0[j];
    v[4 + j] = (bf16)u1[j];
  }
  return v;
}

// ---------------------------------------------------------------------------
// 128x128 GEMM core, BK=32, 4 waves each 64x64 (4x4 tiles of 16x16x32 bf16).
// C[m,n] = sum_k A[m,k] * B[n,k]  (both K-contiguous, lda=ldb=1024).
// LDS rows padded to 40 elems: stride 80B -> bank step 20 -> <=2-way (free).
// ---------------------------------------------------------------------------
#define GP 40  // padded GEMM LDS row pitch
template <bool AF32, bool BF32>
__device__ __forceinline__ void gemm_core(const void* Agv, const void* Bgv,
                                          f32x4 acc[4][4], bf16* As, bf16* Bs) {
  const float* Af = (const float*)Agv;
  const bf16* Ab = (const bf16*)Agv;
  const float* Bf = (const float*)Bgv;
  const bf16* Bb = (const bf16*)Bgv;
  const int tid = threadIdx.x;
  const int lane = tid & 63;
  const int wave = tid >> 6;
  const int wm = (wave >> 1) * 64;
  const int wn = (wave & 1) * 64;
  const int col = lane & 15;
  const int kq = (lane >> 4) * 8;
  const int r0 = tid >> 2;       // staging row (pass 0)
  const int c0 = (tid & 3) * 8;  // staging col
#pragma unroll
  for (int i = 0; i < 4; i++)
#pragma unroll
    for (int j = 0; j < 4; j++) acc[i][j] = (f32x4){0.f, 0.f, 0.f, 0.f};

  for (int k0 = 0; k0 < 1024; k0 += 32) {
    bf16x8 a0, a1, b0, b1;
    if (AF32) {
      a0 = ldcvt(Af + (size_t)r0 * 1024 + k0 + c0);
      a1 = ldcvt(Af + (size_t)(r0 + 64) * 1024 + k0 + c0);
    } else {
      a0 = *(const bf16x8*)(Ab + (size_t)r0 * 1024 + k0 + c0);
      a1 = *(const bf16x8*)(Ab + (size_t)(r0 + 64) * 1024 + k0 + c0);
    }
    if (BF32) {
      b0 = ldcvt(Bf + (size_t)r0 * 1024 + k0 + c0);
      b1 = ldcvt(Bf + (size_t)(r0 + 64) * 1024 + k0 + c0);
    } else {
      b0 = *(const bf16x8*)(Bb + (size_t)r0 * 1024 + k0 + c0);
      b1 = *(const bf16x8*)(Bb + (size_t)(r0 + 64) * 1024 + k0 + c0);
    }
    __syncthreads();  // previous iteration's LDS reads complete
    *(bf16x8*)(As + r0 * GP + c0) = a0;
    *(bf16x8*)(As + (r0 + 64) * GP + c0) = a1;
    *(bf16x8*)(Bs + r0 * GP + c0) = b0;
    *(bf16x8*)(Bs + (r0 + 64) * GP + c0) = b1;
    __syncthreads();

    bf16x8 af[4], bfr[4];
#pragma unroll
    for (int i = 0; i < 4; i++)
      af[i] = *(const bf16x8*)(As + (wm + i * 16 + col) * GP + kq);
#pragma unroll
    for (int j = 0; j < 4; j++)
      bfr[j] = *(const bf16x8*)(Bs + (wn + j * 16 + col) * GP + kq);
#pragma unroll
    for (int i = 0; i < 4; i++)
#pragma unroll
      for (int j = 0; j < 4; j++)
        acc[i][j] = MFMA16(af[i], bfr[j], acc[i][j]);
  }
}

// ---------------------------------------------------------------------------
// Kernel 1: fused QKV projection (f32 in, bf16 out). grid (bcnt*16, 24).
// ---------------------------------------------------------------------------
__global__ __launch_bounds__(256, 2) void qkv_gemm(
    const float* __restrict__ x, const float* __restrict__ wq,
    const float* __restrict__ wk, const float* __restrict__ wv,
    bf16* __restrict__ ws, size_t ten_stride) {
  __shared__ __align__(16) bf16 As[128 * GP];
  __shared__ __align__(16) bf16 Bs[128 * GP];
  const int bx = blockIdx.x;
  const int by = blockIdx.y;
  const int wsel = by >> 3;
  const int n0 = (by & 7) * 128;
  const float* W = (wsel == 0) ? wq : ((wsel == 1) ? wk : wv);
  bf16* dst = ws + (size_t)wsel * ten_stride;

  f32x4 acc[4][4];
  gemm_core<true, true>(x + (size_t)bx * 128 * 1024, W + (size_t)n0 * 1024,
                        acc, As, Bs);

  const int lane = threadIdx.x & 63;
  const int wave = threadIdx.x >> 6;
  const int wm = (wave >> 1) * 64, wn = (wave & 1) * 64;
  const int col = lane & 15, quad = lane >> 4;
#pragma unroll
  for (int i = 0; i < 4; i++) {
    const int m0 = bx * 128 + wm + i * 16 + quad * 4;
#pragma unroll
    for (int j = 0; j < 4; j++) {
      const int n = n0 + wn + j * 16 + col;  // within [0,1024)
      const int h = n >> 6, d = n & 63;
#pragma unroll
      for (int r = 0; r < 4; r++) {
        const int mm = m0 + r;  // pass-local row
        const int bl = mm >> 11, s = mm & 2047;
        dst[((((size_t)bl * NH + h) * S_LEN + s) << 6) + d] = (bf16)acc[i][j][r];
      }
    }
  }
}

// ---------------------------------------------------------------------------
// Kernel 2: RoPE in-place on Q,K (pass-local [bcnt,H,S,D], bf16).
// ---------------------------------------------------------------------------
__global__ void rope_kernel(bf16* __restrict__ q, bf16* __restrict__ k,
                            const int* __restrict__ tp) {
  const int idx = blockIdx.x * 256 + threadIdx.x;
  const int srow = idx >> 3;  // pass-local [0, bcnt*H*S)
  const int d0 = (idx & 7) * 8;
  const int s = srow & (S_LEN - 1);
  const float pf = (float)tp[s];
  const int i0 = d0 >> 1;
  float cs[4], sn[4];
#pragma unroll
  for (int j = 0; j < 4; j++) {
    float freq = __builtin_exp2f(-(float)(i0 + j) * 0.41524101186091903f);
    float ang = pf * freq;
    sincosf(ang, &sn[j], &cs[j]);
  }
  const size_t off = (size_t)srow * 64 + d0;
  bf16x8 vq = *(bf16x8*)(q + off);
  bf16x8 vk = *(bf16x8*)(k + off);
#pragma unroll
  for (int j = 0; j < 4; j++) {
    float e = (float)vq[2 * j], o = (float)vq[2 * j + 1];
    vq[2 * j] = (bf16)(e * cs[j] - o * sn[j]);
    vq[2 * j + 1] = (bf16)(e * sn[j] + o * cs[j]);
    e = (float)vk[2 * j];
    o = (float)vk[2 * j + 1];
    vk[2 * j] = (bf16)(e * cs[j] - o * sn[j]);
    vk[2 * j + 1] = (bf16)(e * sn[j] + o * cs[j]);
  }
  *(bf16x8*)(q + off) = vq;
  *(bf16x8*)(k + off) = vk;
}

// ---------------------------------------------------------------------------
// Kernel 3: V [bh][S][D] -> Vt [bh][D][S] (bf16). grid (32, bcnt*16).
// ---------------------------------------------------------------------------
__global__ void transpose_v(const bf16* __restrict__ v, bf16* __restrict__ vt) {
  __shared__ __align__(16) bf16 t[64 * 72];
  const int st = blockIdx.x, bh = blockIdx.y;
  const bf16* src = v + ((size_t)bh * S_LEN + st * 64) * 64;
#pragma unroll
  for (int p = 0; p < 2; p++) {
    int g = p * 256 + threadIdx.x;
    int r = g >> 3, c = (g & 7) * 8;
    bf16x8 val = *(const bf16x8*)(src + r * 64 + c);
#pragma unroll
    for (int j = 0; j < 8; j++) t[(c + j) * 72 + r] = val[j];
  }
  __syncthreads();
  bf16* dst = vt + (size_t)bh * 64 * S_LEN + st * 64;
#pragma unroll
  for (int p = 0; p < 2; p++) {
    int g = p * 256 + threadIdx.x;
    int d = g >> 3, sc = (g & 7) * 8;
    *(bf16x8*)(dst + (size_t)d * S_LEN + sc) = *(const bf16x8*)(t + d * 72 + sc);
  }
}

// ---------------------------------------------------------------------------
// Kernel 4: causal flash attention, S^T formulation. grid (8, bcnt*16).
// Block j handles q-tiles {15-j, j}: exactly 17 k-iters -> perfect balance.
// S^T = K@Q^T so softmax is register-local (2 xor-shuffles per q-16-group);
// P written as conflict-free ds_write_b64 into a per-wave chunk buffer.
// LDS 54.3KB: Ks[128][72] | Vts[64][136] | P 4x[32][72]. 2 barriers/iter.
// ---------------------------------------------------------------------------
#define KP 72   // Ks row pitch
#define VP 136  // Vts row pitch
#define PP 72   // P chunk row pitch (64 keys + pad)
__global__ __launch_bounds__(256, 2) void attn_kernel(
    const bf16* __restrict__ Q, const bf16* __restrict__ K,
    const bf16* __restrict__ Vt, bf16* __restrict__ O) {
  __shared__ __align__(16) bf16 Ks[128 * KP];      // 18,432 B
  __shared__ __align__(16) bf16 Vts[64 * VP];      // 17,408 B
  __shared__ __align__(16) bf16 Ps[4 * 32 * PP];   // 18,432 B

  const int tid = threadIdx.x, lane = tid & 63, wave = tid >> 6;
  const int col = lane & 15, quad = lane >> 4, kq = quad * 8;
  const int bh = blockIdx.y;  // pass-local
  const int bl = bh >> 4, h = bh & 15;
  const bf16* Kg = K + (size_t)bh * S_LEN * 64;
  const bf16* Vg = Vt + (size_t)bh * 64 * S_LEN;
  bf16* Pw = Ps + wave * 32 * PP;
  const int wq0 = wave * 32;
  const float CS = 0.18033688011112042f;  // 0.125 * log2(e)

  for (int half = 0; half < 2; half++) {
    const int qt = half ? (int)blockIdx.x : 15 - (int)blockIdx.x;
    // Q fragments straight from global (16B per load, no LDS staging)
    const bf16* Qg = Q + ((size_t)bh * S_LEN + qt * 128) * 64;
    bf16x8 qf[2][2];
#pragma unroll
    for (int mi = 0; mi < 2; mi++)
#pragma unroll
      for (int kc = 0; kc < 2; kc++)
        qf[mi][kc] =
            *(const bf16x8*)(Qg + (wq0 + mi * 16 + col) * 64 + kc * 32 + kq);

    f32x4 oacc[2][4];
    float mst[2] = {-1e30f, -1e30f}, lst[2] = {0.f, 0.f};
#pragma unroll
    for (int mi = 0; mi < 2; mi++)
#pragma unroll
      for (int nd = 0; nd < 4; nd++) oacc[mi][nd] = (f32x4){0.f, 0.f, 0.f, 0.f};

    for (int kt = 0; kt <= qt; kt++) {
      // stage K (128x64) and Vt (64x128), register-mediated
      bf16x8 kreg[4], vreg[4];
#pragma unroll
      for (int p = 0; p < 4; p++) {
        int g = p * 256 + tid;
        kreg[p] = *(const bf16x8*)(Kg + (size_t)(kt * 128 + (g >> 3)) * 64 +
                                   (g & 7) * 8);
        vreg[p] = *(const bf16x8*)(Vg + (size_t)(g >> 4) * S_LEN + kt * 128 +
                                   (g & 15) * 8);
      }
      __syncthreads();  // previous iteration's LDS reads complete
#pragma unroll
      for (int p = 0; p < 4; p++) {
        int g = p * 256 + tid;
        *(bf16x8*)(Ks + (g >> 3) * KP + (g & 7) * 8) = kreg[p];
        *(bf16x8*)(Vts + (g >> 4) * VP + (g & 15) * 8) = vreg[p];
      }
      __syncthreads();

      // S^T[key][q]: A=K-frag (m=key), B=Q-frag (n=q); K=64 via 2 chained
      f32x4 sa[2][8];
#pragma unroll
      for (int ni = 0; ni < 8; ni++) {
        bf16x8 kf0 = *(const bf16x8*)(Ks + (ni * 16 + col) * KP + kq);
        bf16x8 kf1 = *(const bf16x8*)(Ks + (ni * 16 + col) * KP + 32 + kq);
#pragma unroll
        for (int mi = 0; mi < 2; mi++) {
          f32x4 s = {0.f, 0.f, 0.f, 0.f};
          s = MFMA16(kf0, qf[mi][0], s);
          s = MFMA16(kf1, qf[mi][1], s);
          sa[mi][ni] = s;  // reg r: key=ni*16+quad*4+r, q=mi*16+col
        }
      }
      if (kt == qt) {  // causal mask on the diagonal tile
#pragma unroll
        for (int mi = 0; mi < 2; mi++) {
          const int qloc = wq0 + mi * 16 + col;
#pragma unroll
          for (int ni = 0; ni < 8; ni++)
#pragma unroll
            for (int r = 0; r < 4; r++)
              if (ni * 16 + quad * 4 + r > qloc) sa[mi][ni][r] = -1e30f;
        }
      }
      // Online softmax: per q (=mi*16+col), keys spread over regs + quads
#pragma unroll
      for (int mi = 0; mi < 2; mi++) {
        float mx = sa[mi][0][0];
#pragma unroll
        for (int ni = 0; ni < 8; ni++)
#pragma unroll
          for (int r = 0; r < 4; r++) mx = fmaxf(mx, sa[mi][ni][r]);
        mx = fmaxf(mx, __shfl_xor(mx, 16));
        mx = fmaxf(mx, __shfl_xor(mx, 32));
        const float mnew = fmaxf(mst[mi], mx);
        const float alpha = __builtin_exp2f((mst[mi] - mnew) * CS);
        mst[mi] = mnew;
        float rs = 0.f;
#pragma unroll
        for (int ni = 0; ni < 8; ni++)
#pragma unroll
          for (int r = 0; r < 4; r++) {
            float pv = __builtin_exp2f((sa[mi][ni][r] - mnew) * CS);
            sa[mi][ni][r] = pv;
            rs += pv;
          }
        rs += __shfl_xor(rs, 16);
        rs += __shfl_xor(rs, 32);
        lst[mi] = lst[mi] * alpha + rs;
        // transpose alpha to O layout (q = quad*4+r) via bpermute
        float av[4];
#pragma unroll
        for (int r = 0; r < 4; r++) av[r] = __shfl(alpha, quad * 4 + r);
#pragma unroll
        for (int nd = 0; nd < 4; nd++)
#pragma unroll
          for (int r = 0; r < 4; r++) oacc[mi][nd][r] *= av[r];
      }
      // PV in two 64-key halves through the per-wave chunk buffer
#pragma unroll
      for (int hf = 0; hf < 2; hf++) {
#pragma unroll
        for (int mi = 0; mi < 2; mi++)
#pragma unroll
          for (int nn = 0; nn < 4; nn++) {
            const int ni = hf * 4 + nn;
            bf16x4 pk;
#pragma unroll
            for (int r = 0; r < 4; r++) pk[r] = (bf16)sa[mi][ni][r];
            *(bf16x4*)(Pw + (mi * 16 + col) * PP + nn * 16 + quad * 4) = pk;
          }
        // per-wave buffer: compiler-ordered DS ops, no barrier needed
#pragma unroll
        for (int kcl = 0; kcl < 2; kcl++) {
          const int kc = hf * 2 + kcl;
          bf16x8 pf0 = *(const bf16x8*)(Pw + col * PP + kcl * 32 + kq);
          bf16x8 pf1 = *(const bf16x8*)(Pw + (16 + col) * PP + kcl * 32 + kq);
#pragma unroll
          for (int nd = 0; nd < 4; nd++) {
            bf16x8 vf =
                *(const bf16x8*)(Vts + (nd * 16 + col) * VP + kc * 32 + kq);
            oacc[0][nd] = MFMA16(pf0, vf, oacc[0][nd]);
            oacc[1][nd] = MFMA16(pf1, vf, oacc[1][nd]);
          }
        }
      }
    }

    // Epilogue: O[bl][s][h*64+d] = oacc / l   (O layout: d=col, q=quad*4+r)
#pragma unroll
    for (int mi = 0; mi < 2; mi++) {
      const float il = 1.0f / lst[mi];
      float linv[4];
#pragma unroll
      for (int r = 0; r < 4; r++) linv[r] = __shfl(il, quad * 4 + r);
      const int srow0 = qt * 128 + wq0 + mi * 16 + quad * 4;
#pragma unroll
      for (int nd = 0; nd < 4; nd++)
#pragma unroll
        for (int r = 0; r < 4; r++)
          O[(size_t)(bl * S_LEN + srow0 + r) * DM + h * 64 + nd * 16 + col] =
              (bf16)(oacc[mi][nd][r] * linv[r]);
    }
  }
}

// ---------------------------------------------------------------------------
// Kernel 5: output projection (A bf16, W f32, out f32). grid (bcnt*16, 8).
// ---------------------------------------------------------------------------
__global__ __launch_bounds__(256, 2) void out_gemm(const bf16* __restrict__ A,
                                                   const float* __restrict__ W,
                                                   float* __restrict__ out) {
  __shared__ __align__(16) bf16 As[128 * GP];
  __shared__ __align__(16) bf16 Bs[128 * GP];
  f32x4 acc[4][4];
  gemm_core<false, true>(A + (size_t)blockIdx.x * 128 * 1024,
                         W + (size_t)blockIdx.y * 128 * 1024, acc, As, Bs);
  const int lane = threadIdx.x & 63;
  const int wave = threadIdx.x >> 6;
  const int wm = (wave >> 1) * 64, wn = (wave & 1) * 64;
  const int col = lane & 15, quad = lane >> 4;
#pragma unroll
  for (int i = 0; i < 4; i++) {
    const int m0 = blockIdx.x * 128 + wm + i * 16 + quad * 4;
#pragma unroll
    for (int j = 0; j < 4; j++) {
      const int n = blockIdx.y * 128 + wn + j * 16 + col;
#pragma unroll
      for (int r = 0; r < 4; r++)
        out[(size_t)(m0 + r) * DM + n] = acc[i][j][r];
    }
  }
}

// ---------------------------------------------------------------------------
extern "C" void kernel_launch(void* const* d_in, const int* in_sizes, int n_in,
                              void* d_out, int out_size, void* d_ws,
                              size_t ws_size, hipStream_t stream) {
  const float* x = (const float*)d_in[0];
  const int* tp = (const int*)d_in[1];
  const float* wq = (const float*)d_in[2];
  const float* wk = (const float*)d_in[3];
  const float* wv = (const float*)d_in[4];
  const float* wo = (const float*)d_in[5];
  float* out = (float*)d_out;
  bf16* wsb = (bf16*)d_ws;

  const size_t TENb = (size_t)NH * S_LEN * HD;  // per-batch tensor: 4 MB bf16
  int bcnt = 1;
  if (ws_size >= 4 * 4 * TENb * sizeof(bf16)) bcnt = 4;       // 64 MB
  else if (ws_size >= 2 * 4 * TENb * sizeof(bf16)) bcnt = 2;  // 32 MB

  const size_t REG = (size_t)bcnt * TENb;
  bf16* Qw = wsb;             // [bcnt,H,S,D]
  bf16* Kw = wsb + REG;       // [bcnt,H,S,D]
  bf16* Vw = wsb + 2 * REG;   // [bcnt,H,S,D]
  bf16* Vtw = wsb + 3 * REG;  // [bcnt,H,D,S]
  bf16* Ow = Vw;              // [bcnt,S,H*D], aliases Vw (dead after transpose)

  for (int b0 = 0; b0 < B_SZ; b0 += bcnt) {
    const float* xb = x + (size_t)b0 * S_LEN * DM;
    float* outb = out + (size_t)b0 * S_LEN * DM;
    hipLaunchKernelGGL(qkv_gemm, dim3(bcnt * 16, 24), dim3(256), 0, stream,
                       xb, wq, wk, wv, Qw, REG);
    hipLaunchKernelGGL(rope_kernel, dim3(bcnt * 1024), dim3(256), 0, stream,
                       Qw, Kw, tp);
    hipLaunchKernelGGL(transpose_v, dim3(32, bcnt * 16), dim3(256), 0, stream,
                       Vw, Vtw);
    hipLaunchKernelGGL(attn_kernel, dim3(8, bcnt * 16), dim3(256), 0, stream,
                       Qw, Kw, Vtw, Ow);
    hipLaunchKernelGGL(out_gemm, dim3(bcnt * 16, 8), dim3(256), 0, stream,
                       Ow, wo, outb);
  }
}

// Round 5
// 279.054 us; speedup vs baseline: 2.1368x; 1.1037x over previous
//
#include <hip/hip_runtime.h>
#include <stdint.h>

// Problem constants
#define B_SZ 4
#define S_LEN 2048
#define NH 16
#define HD 64
#define DM 1024

typedef __bf16 bf16;
typedef __bf16 bf16x4 __attribute__((ext_vector_type(4)));
typedef __bf16 bf16x8 __attribute__((ext_vector_type(8)));
typedef float f32x4 __attribute__((ext_vector_type(4)));

#define MFMA16(a, b, c) __builtin_amdgcn_mfma_f32_16x16x32_bf16(a, b, c, 0, 0, 0)

__device__ __forceinline__ void gl2lds16(const void* g, void* l) {
  __builtin_amdgcn_global_load_lds(
      (__attribute__((address_space(1))) const void*)g,
      (__attribute__((address_space(3))) void*)l, 16, 0, 0);
}

// load 8 consecutive f32 and round to bf16x8
__device__ __forceinline__ bf16x8 ldcvt(const float* p) {
  f32x4 u0 = *(const f32x4*)p;
  f32x4 u1 = *(const f32x4*)(p + 4);
  bf16x8 v;
#pragma unroll
  for (int j = 0; j < 4; j++) {
    v[j] = (bf16)u0[j];
    v[4 + j] = (bf16)u1[j];
  }
  return v;
}

// ---------------------------------------------------------------------------
// Kernel 0: f32 -> bf16 conversion of x-chunk and the 4 weight matrices.
// ---------------------------------------------------------------------------
__global__ void cvt_kernel(const float* __restrict__ x,
                           const float* __restrict__ wq,
                           const float* __restrict__ wk,
                           const float* __restrict__ wv,
                           const float* __restrict__ wo,
                           bf16* __restrict__ Xb, bf16* __restrict__ Wb,
                           long xN) {
  const long e = ((long)blockIdx.x * 256 + threadIdx.x) * 8;
  const float* src;
  bf16* dst;
  long off;
  if (e < xN) {
    src = x; dst = Xb; off = e;
  } else {
    const long w = e - xN;
    const int wi = (int)(w >> 20);  // 1M elems per weight
    src = (wi == 0) ? wq : (wi == 1) ? wk : (wi == 2) ? wv : wo;
    dst = Wb + ((size_t)wi << 20);
    off = w & ((1L << 20) - 1);
  }
  *(bf16x8*)(dst + off) = ldcvt(src + off);
}

// ---------------------------------------------------------------------------
// 128x128 GEMM core (m97 structure): BK=32, global_load_lds width-16,
// unpadded [128][32] LDS, 2 barriers/iter. C[m,n] = sum_k A[m,k]*B[n,k],
// both bf16, lda = ldb = 1024.
// ---------------------------------------------------------------------------
__device__ __forceinline__ void gemm_core_bb(const bf16* __restrict__ Ag,
                                             const bf16* __restrict__ Bg,
                                             f32x4 acc[4][4], bf16* As,
                                             bf16* Bs) {
  const int tid = threadIdx.x;
  const int lane = tid & 63;
  const int wave = tid >> 6;
  const int wm = (wave >> 1) * 64;
  const int wn = (wave & 1) * 64;
  const int col = lane & 15;
  const int kq = (lane >> 4) * 8;
  const int r0 = tid >> 2;       // staging row (pass 0)
  const int c0 = (tid & 3) * 8;  // staging col
#pragma unroll
  for (int i = 0; i < 4; i++)
#pragma unroll
    for (int j = 0; j < 4; j++) acc[i][j] = (f32x4){0.f, 0.f, 0.f, 0.f};

  for (int k0 = 0; k0 < 1024; k0 += 32) {
    __syncthreads();  // previous iteration's LDS reads complete
    gl2lds16(Ag + (size_t)r0 * 1024 + k0 + c0, As + tid * 8);
    gl2lds16(Ag + (size_t)(r0 + 64) * 1024 + k0 + c0, As + 2048 + tid * 8);
    gl2lds16(Bg + (size_t)r0 * 1024 + k0 + c0, Bs + tid * 8);
    gl2lds16(Bg + (size_t)(r0 + 64) * 1024 + k0 + c0, Bs + 2048 + tid * 8);
    __syncthreads();  // drains vmcnt -> LDS data visible

    bf16x8 af[4], bfr[4];
#pragma unroll
    for (int i = 0; i < 4; i++)
      af[i] = *(const bf16x8*)(As + (wm + i * 16 + col) * 32 + kq);
#pragma unroll
    for (int j = 0; j < 4; j++)
      bfr[j] = *(const bf16x8*)(Bs + (wn + j * 16 + col) * 32 + kq);
#pragma unroll
    for (int i = 0; i < 4; i++)
#pragma unroll
      for (int j = 0; j < 4; j++)
        acc[i][j] = MFMA16(af[i], bfr[j], acc[i][j]);
  }
}

// ---------------------------------------------------------------------------
// Kernel 1: fused QKV projection (bf16 in/out) + fused V transpose.
// grid (bcnt*16, 24). wsel 0/1 -> Q/K [bh][s][d]; wsel 2 -> Vt [bh][d][s].
// ---------------------------------------------------------------------------
__global__ __launch_bounds__(256, 4) void qkv_gemm(
    const bf16* __restrict__ x, const bf16* __restrict__ Wb,
    bf16* __restrict__ Q, bf16* __restrict__ K, bf16* __restrict__ Vt) {
  __shared__ __align__(16) bf16 As[128 * 32];
  __shared__ __align__(16) bf16 Bs[128 * 32];
  const int bx = blockIdx.x;
  const int by = blockIdx.y;
  const int wsel = by >> 3;
  const int n0 = (by & 7) * 128;

  f32x4 acc[4][4];
  gemm_core_bb(x + (size_t)bx * 128 * 1024,
               Wb + ((size_t)wsel << 20) + (size_t)n0 * 1024, acc, As, Bs);

  const int lane = threadIdx.x & 63;
  const int wave = threadIdx.x >> 6;
  const int wm = (wave >> 1) * 64, wn = (wave & 1) * 64;
  const int col = lane & 15, quad = lane >> 4;

  if (wsel < 2) {
    bf16* dst = wsel ? K : Q;
#pragma unroll
    for (int i = 0; i < 4; i++) {
      const int m0 = bx * 128 + wm + i * 16 + quad * 4;
#pragma unroll
      for (int j = 0; j < 4; j++) {
        const int n = n0 + wn + j * 16 + col;  // [0,1024)
        const int h = n >> 6, d = n & 63;
#pragma unroll
        for (int r = 0; r < 4; r++) {
          const int mm = m0 + r;  // pass-local row
          const int bl = mm >> 11, s = mm & 2047;
          dst[((((size_t)bl * NH + h) * S_LEN + s) << 6) + d] =
              (bf16)acc[i][j][r];
        }
      }
    }
  } else {  // V: write transposed [bh][d][s], 4 consecutive s per store
#pragma unroll
    for (int i = 0; i < 4; i++) {
      const int m0 = bx * 128 + wm + i * 16 + quad * 4;
      const int bl = m0 >> 11, s = m0 & 2047;
#pragma unroll
      for (int j = 0; j < 4; j++) {
        const int n = n0 + wn + j * 16 + col;
        const int h = n >> 6, d = n & 63;
        bf16x4 pk;
#pragma unroll
        for (int r = 0; r < 4; r++) pk[r] = (bf16)acc[i][j][r];
        *(bf16x4*)(Vt + (((size_t)(bl * NH + h) * 64 + d) << 11) + s) = pk;
      }
    }
  }
}

// ---------------------------------------------------------------------------
// Kernel 2: RoPE in-place on Q,K (pass-local [bcnt,H,S,D], bf16).
// ---------------------------------------------------------------------------
__global__ void rope_kernel(bf16* __restrict__ q, bf16* __restrict__ k,
                            const int* __restrict__ tp) {
  const int idx = blockIdx.x * 256 + threadIdx.x;
  const int srow = idx >> 3;  // pass-local [0, bcnt*H*S)
  const int d0 = (idx & 7) * 8;
  const int s = srow & (S_LEN - 1);
  const float pf = (float)tp[s];
  const int i0 = d0 >> 1;
  float cs[4], sn[4];
#pragma unroll
  for (int j = 0; j < 4; j++) {
    float freq = __builtin_exp2f(-(float)(i0 + j) * 0.41524101186091903f);
    float ang = pf * freq;
    sincosf(ang, &sn[j], &cs[j]);
  }
  const size_t off = (size_t)srow * 64 + d0;
  bf16x8 vq = *(bf16x8*)(q + off);
  bf16x8 vk = *(bf16x8*)(k + off);
#pragma unroll
  for (int j = 0; j < 4; j++) {
    float e = (float)vq[2 * j], o = (float)vq[2 * j + 1];
    vq[2 * j] = (bf16)(e * cs[j] - o * sn[j]);
    vq[2 * j + 1] = (bf16)(e * sn[j] + o * cs[j]);
    e = (float)vk[2 * j];
    o = (float)vk[2 * j + 1];
    vk[2 * j] = (bf16)(e * cs[j] - o * sn[j]);
    vk[2 * j + 1] = (bf16)(e * sn[j] + o * cs[j]);
  }
  *(bf16x8*)(q + off) = vq;
  *(bf16x8*)(k + off) = vk;
}

// ---------------------------------------------------------------------------
// Kernel 4: causal flash attention, S^T formulation. grid (8, bcnt*16).
// Block j handles q-tiles {15-j, j}: exactly 17 k-iters -> perfect balance.
// LDS 54.3KB padded conflict-free: Ks[128][72] | Vts[64][136] | P 4x[32][72].
// ---------------------------------------------------------------------------
#define KP 72   // Ks row pitch
#define VP 136  // Vts row pitch
#define PP 72   // P chunk row pitch
__global__ __launch_bounds__(256, 2) void attn_kernel(
    const bf16* __restrict__ Q, const bf16* __restrict__ K,
    const bf16* __restrict__ Vt, bf16* __restrict__ O) {
  __shared__ __align__(16) bf16 Ks[128 * KP];
  __shared__ __align__(16) bf16 Vts[64 * VP];
  __shared__ __align__(16) bf16 Ps[4 * 32 * PP];

  const int tid = threadIdx.x, lane = tid & 63, wave = tid >> 6;
  const int col = lane & 15, quad = lane >> 4, kq = quad * 8;
  const int bh = blockIdx.y;  // pass-local
  const int bl = bh >> 4, h = bh & 15;
  const bf16* Kg = K + (size_t)bh * S_LEN * 64;
  const bf16* Vg = Vt + (size_t)bh * 64 * S_LEN;
  bf16* Pw = Ps + wave * 32 * PP;
  const int wq0 = wave * 32;
  const float CS = 0.18033688011112042f;  // 0.125 * log2(e)

  for (int half = 0; half < 2; half++) {
    const int qt = half ? (int)blockIdx.x : 15 - (int)blockIdx.x;
    const bf16* Qg = Q + ((size_t)bh * S_LEN + qt * 128) * 64;
    bf16x8 qf[2][2];
#pragma unroll
    for (int mi = 0; mi < 2; mi++)
#pragma unroll
      for (int kc = 0; kc < 2; kc++)
        qf[mi][kc] =
            *(const bf16x8*)(Qg + (wq0 + mi * 16 + col) * 64 + kc * 32 + kq);

    f32x4 oacc[2][4];
    float mst[2] = {-1e30f, -1e30f}, lst[2] = {0.f, 0.f};
#pragma unroll
    for (int mi = 0; mi < 2; mi++)
#pragma unroll
      for (int nd = 0; nd < 4; nd++) oacc[mi][nd] = (f32x4){0.f, 0.f, 0.f, 0.f};

    for (int kt = 0; kt <= qt; kt++) {
      bf16x8 kreg[4], vreg[4];
#pragma unroll
      for (int p = 0; p < 4; p++) {
        int g = p * 256 + tid;
        kreg[p] = *(const bf16x8*)(Kg + (size_t)(kt * 128 + (g >> 3)) * 64 +
                                   (g & 7) * 8);
        vreg[p] = *(const bf16x8*)(Vg + (size_t)(g >> 4) * S_LEN + kt * 128 +
                                   (g & 15) * 8);
      }
      __syncthreads();
#pragma unroll
      for (int p = 0; p < 4; p++) {
        int g = p * 256 + tid;
        *(bf16x8*)(Ks + (g >> 3) * KP + (g & 7) * 8) = kreg[p];
        *(bf16x8*)(Vts + (g >> 4) * VP + (g & 15) * 8) = vreg[p];
      }
      __syncthreads();

      f32x4 sa[2][8];
#pragma unroll
      for (int ni = 0; ni < 8; ni++) {
        bf16x8 kf0 = *(const bf16x8*)(Ks + (ni * 16 + col) * KP + kq);
        bf16x8 kf1 = *(const bf16x8*)(Ks + (ni * 16 + col) * KP + 32 + kq);
#pragma unroll
        for (int mi = 0; mi < 2; mi++) {
          f32x4 s = {0.f, 0.f, 0.f, 0.f};
          s = MFMA16(kf0, qf[mi][0], s);
          s = MFMA16(kf1, qf[mi][1], s);
          sa[mi][ni] = s;  // reg r: key=ni*16+quad*4+r, q=mi*16+col
        }
      }
      if (kt == qt) {
#pragma unroll
        for (int mi = 0; mi < 2; mi++) {
          const int qloc = wq0 + mi * 16 + col;
#pragma unroll
          for (int ni = 0; ni < 8; ni++)
#pragma unroll
            for (int r = 0; r < 4; r++)
              if (ni * 16 + quad * 4 + r > qloc) sa[mi][ni][r] = -1e30f;
        }
      }
#pragma unroll
      for (int mi = 0; mi < 2; mi++) {
        float mx = sa[mi][0][0];
#pragma unroll
        for (int ni = 0; ni < 8; ni++)
#pragma unroll
          for (int r = 0; r < 4; r++) mx = fmaxf(mx, sa[mi][ni][r]);
        mx = fmaxf(mx, __shfl_xor(mx, 16));
        mx = fmaxf(mx, __shfl_xor(mx, 32));
        const float mnew = fmaxf(mst[mi], mx);
        const float alpha = __builtin_exp2f((mst[mi] - mnew) * CS);
        mst[mi] = mnew;
        float rs = 0.f;
#pragma unroll
        for (int ni = 0; ni < 8; ni++)
#pragma unroll
          for (int r = 0; r < 4; r++) {
            float pv = __builtin_exp2f((sa[mi][ni][r] - mnew) * CS);
            sa[mi][ni][r] = pv;
            rs += pv;
          }
        rs += __shfl_xor(rs, 16);
        rs += __shfl_xor(rs, 32);
        lst[mi] = lst[mi] * alpha + rs;
        float av[4];
#pragma unroll
        for (int r = 0; r < 4; r++) av[r] = __shfl(alpha, quad * 4 + r);
#pragma unroll
        for (int nd = 0; nd < 4; nd++)
#pragma unroll
          for (int r = 0; r < 4; r++) oacc[mi][nd][r] *= av[r];
      }
#pragma unroll
      for (int hf = 0; hf < 2; hf++) {
#pragma unroll
        for (int mi = 0; mi < 2; mi++)
#pragma unroll
          for (int nn = 0; nn < 4; nn++) {
            const int ni = hf * 4 + nn;
            bf16x4 pk;
#pragma unroll
            for (int r = 0; r < 4; r++) pk[r] = (bf16)sa[mi][ni][r];
            *(bf16x4*)(Pw + (mi * 16 + col) * PP + nn * 16 + quad * 4) = pk;
          }
#pragma unroll
        for (int kcl = 0; kcl < 2; kcl++) {
          const int kc = hf * 2 + kcl;
          bf16x8 pf0 = *(const bf16x8*)(Pw + col * PP + kcl * 32 + kq);
          bf16x8 pf1 = *(const bf16x8*)(Pw + (16 + col) * PP + kcl * 32 + kq);
#pragma unroll
          for (int nd = 0; nd < 4; nd++) {
            bf16x8 vf =
                *(const bf16x8*)(Vts + (nd * 16 + col) * VP + kc * 32 + kq);
            oacc[0][nd] = MFMA16(pf0, vf, oacc[0][nd]);
            oacc[1][nd] = MFMA16(pf1, vf, oacc[1][nd]);
          }
        }
      }
    }

#pragma unroll
    for (int mi = 0; mi < 2; mi++) {
      const float il = 1.0f / lst[mi];
      float linv[4];
#pragma unroll
      for (int r = 0; r < 4; r++) linv[r] = __shfl(il, quad * 4 + r);
      const int srow0 = qt * 128 + wq0 + mi * 16 + quad * 4;
#pragma unroll
      for (int nd = 0; nd < 4; nd++)
#pragma unroll
        for (int r = 0; r < 4; r++)
          O[(size_t)(bl * S_LEN + srow0 + r) * DM + h * 64 + nd * 16 + col] =
              (bf16)(oacc[mi][nd][r] * linv[r]);
    }
  }
}

// ---------------------------------------------------------------------------
// Kernel 5: output projection (A bf16, W bf16, out f32). grid (bcnt*16, 8).
// ---------------------------------------------------------------------------
__global__ __launch_bounds__(256, 4) void out_gemm(const bf16* __restrict__ A,
                                                   const bf16* __restrict__ W,
                                                   float* __restrict__ out) {
  __shared__ __align__(16) bf16 As[128 * 32];
  __shared__ __align__(16) bf16 Bs[128 * 32];
  f32x4 acc[4][4];
  gemm_core_bb(A + (size_t)blockIdx.x * 128 * 1024,
               W + (size_t)blockIdx.y * 128 * 1024, acc, As, Bs);
  const int lane = threadIdx.x & 63;
  const int wave = threadIdx.x >> 6;
  const int wm = (wave >> 1) * 64, wn = (wave & 1) * 64;
  const int col = lane & 15, quad = lane >> 4;
#pragma unroll
  for (int i = 0; i < 4; i++) {
    const int m0 = blockIdx.x * 128 + wm + i * 16 + quad * 4;
#pragma unroll
    for (int j = 0; j < 4; j++) {
      const int n = blockIdx.y * 128 + wn + j * 16 + col;
#pragma unroll
      for (int r = 0; r < 4; r++)
        out[(size_t)(m0 + r) * DM + n] = acc[i][j][r];
    }
  }
}

// ---------------------------------------------------------------------------
extern "C" void kernel_launch(void* const* d_in, const int* in_sizes, int n_in,
                              void* d_out, int out_size, void* d_ws,
                              size_t ws_size, hipStream_t stream) {
  const float* x = (const float*)d_in[0];
  const int* tp = (const int*)d_in[1];
  const float* wq = (const float*)d_in[2];
  const float* wk = (const float*)d_in[3];
  const float* wv = (const float*)d_in[4];
  const float* wo = (const float*)d_in[5];
  float* out = (float*)d_out;
  bf16* wsb = (bf16*)d_ws;

  const size_t TENb = (size_t)NH * S_LEN * HD;  // 2M elems = per-batch tensor
  const size_t WSZ = 4ull * DM * DM;            // 4M elems (4 bf16 weights)
  // need (4 regions * bcnt * TENb + WSZ) bf16 elems
  int bcnt = 1;
  if (ws_size >= (4 * 4 * TENb + WSZ) * sizeof(bf16)) bcnt = 4;       // 72 MB
  else if (ws_size >= (4 * 2 * TENb + WSZ) * sizeof(bf16)) bcnt = 2;  // 40 MB

  const size_t REG = (size_t)bcnt * TENb;
  bf16* Xb = wsb;             // [bcnt,S,DM] bf16 x; later aliased by Ow
  bf16* Qw = wsb + REG;       // [bcnt,H,S,D]
  bf16* Kw = wsb + 2 * REG;   // [bcnt,H,S,D]
  bf16* Vtw = wsb + 3 * REG;  // [bcnt,H,D,S]
  bf16* Wb = wsb + 4 * REG;   // [4,DM,DM] bf16 weights (wq|wk|wv|wo)
  bf16* Ow = Xb;              // [bcnt,S,H*D], x dead after qkv_gemm

  for (int b0 = 0; b0 < B_SZ; b0 += bcnt) {
    const float* xb = x + (size_t)b0 * S_LEN * DM;
    float* outb = out + (size_t)b0 * S_LEN * DM;
    const long cvtN = (long)(REG + WSZ);  // elems, divisible by 2048
    hipLaunchKernelGGL(cvt_kernel, dim3((unsigned)(cvtN / 2048)), dim3(256), 0,
                       stream, xb, wq, wk, wv, wo, Xb, Wb, (long)REG);
    hipLaunchKernelGGL(qkv_gemm, dim3(bcnt * 16, 24), dim3(256), 0, stream,
                       Xb, Wb, Qw, Kw, Vtw);
    hipLaunchKernelGGL(rope_kernel, dim3(bcnt * 1024), dim3(256), 0, stream,
                       Qw, Kw, tp);
    hipLaunchKernelGGL(attn_kernel, dim3(8, bcnt * 16), dim3(256), 0, stream,
                       Qw, Kw, Vtw, Ow);
    hipLaunchKernelGGL(out_gemm, dim3(bcnt * 16, 8), dim3(256), 0, stream,
                       Ow, Wb + 3ull * DM * DM, outb);
  }
}